// Round 12
// baseline (437.554 us; speedup 1.0000x reference)
//
#include <hip/hip_runtime.h>

// Attention block: x_s = softmax(qk^T)[:4096,4096:] @ query @ Wps^T
//                  x_q = softmax(qk^T)[4096:,:4096] @ s     @ Wpq^T
// R22: R21 + one change: PV tile 128x128 -> 128x64 (grid 1024 = 3 blocks/CU
// by 48KB LDS, 24 waves/CU — the per-CU regime every measurement this
// session ranks best; scores 3blk/CU beat 2 and 5, PV wave-count wins R20+
// R21). BK=128 kept. Wave grid 4Mx2N, wave-tile 32x32, acc[2][2]. Known
// cost: LDS-read/MFMA 0.75 -> 1.0 b128 (accepted: R20's +50% read ratio
// still won; PV is latency/barrier-bound, not LDS-BW-bound). Swizzle =
// R21's verified BK=128 involution; B-tile bank check: 2 lanes/bank = free.
// prep (R0) / qkv 256x128+XCDswz (R13) / scores 256x128 R0-exact (R18).

typedef unsigned short u16;
typedef __bf16 bf16x8 __attribute__((ext_vector_type(8)));
typedef float f32x4 __attribute__((ext_vector_type(4)));
typedef unsigned short u16x8 __attribute__((ext_vector_type(8)));

#define DEVI static __device__ __forceinline__

DEVI u16 f2b(float f) {  // fp32 -> bf16 round-to-nearest-even
  unsigned int u = __float_as_uint(f);
  u += 0x7fffu + ((u >> 16) & 1u);
  return (u16)(u >> 16);
}

DEVI float exp2_hw(float x) {  // v_exp_f32: 2^x
  float r;
  asm("v_exp_f32 %0, %1" : "=v"(r) : "v"(x));
  return r;
}

// ---------------- fused prep (unchanged) ----------------
__global__ void prep_all(const float* __restrict__ query, const float* __restrict__ s,
                         const float* __restrict__ tg, const float* __restrict__ w0,
                         const float* __restrict__ w1, const float* __restrict__ w2,
                         u16* __restrict__ cB, u16* __restrict__ sBf,
                         u16* __restrict__ o0, u16* __restrict__ o1,
                         u16* __restrict__ o2, float* __restrict__ rowsum) {
  int b = blockIdx.x;
  if (b >= 6144) {
    int i = (b - 6144) * 1024 + (int)threadIdx.x * 4;
    rowsum[i] = 0.f; rowsum[i + 1] = 0.f; rowsum[i + 2] = 0.f; rowsum[i + 3] = 0.f;
    return;
  }
  if (b < 4096) {
    int base = (b * 256 + threadIdx.x) << 3;
    int row = base >> 10;
    u16x8 o;
    if (row < 4096) {
      float4 a0 = *(const float4*)(s + base);
      float4 a1 = *(const float4*)(s + base + 4);
      float4 b0 = *(const float4*)(tg + base);
      float4 b1 = *(const float4*)(tg + base + 4);
      u16x8 os;
      os[0] = f2b(a0.x); os[1] = f2b(a0.y); os[2] = f2b(a0.z); os[3] = f2b(a0.w);
      os[4] = f2b(a1.x); os[5] = f2b(a1.y); os[6] = f2b(a1.z); os[7] = f2b(a1.w);
      *(u16x8*)(sBf + base) = os;
      o[0] = f2b(a0.x + b0.x); o[1] = f2b(a0.y + b0.y);
      o[2] = f2b(a0.z + b0.z); o[3] = f2b(a0.w + b0.w);
      o[4] = f2b(a1.x + b1.x); o[5] = f2b(a1.y + b1.y);
      o[6] = f2b(a1.z + b1.z); o[7] = f2b(a1.w + b1.w);
    } else {
      int qb = base - 4096 * 1024;
      float4 a0 = *(const float4*)(query + qb);
      float4 a1 = *(const float4*)(query + qb + 4);
      o[0] = f2b(a0.x); o[1] = f2b(a0.y); o[2] = f2b(a0.z); o[3] = f2b(a0.w);
      o[4] = f2b(a1.x); o[5] = f2b(a1.y); o[6] = f2b(a1.z); o[7] = f2b(a1.w);
    }
    *(u16x8*)(cB + base) = o;
  } else {
    const float* in; u16* out; int lb;
    if (b < 5120)      { in = w0; out = o0; lb = b - 4096; }
    else if (b < 5632) { in = w1; out = o1; lb = b - 5120; }
    else               { in = w2; out = o2; lb = b - 5632; }
    int base = (lb * 256 + threadIdx.x) << 3;
    float4 a0 = *(const float4*)(in + base);
    float4 a1 = *(const float4*)(in + base + 4);
    u16x8 o;
    o[0] = f2b(a0.x); o[1] = f2b(a0.y); o[2] = f2b(a0.z); o[3] = f2b(a0.w);
    o[4] = f2b(a1.x); o[5] = f2b(a1.y); o[6] = f2b(a1.z); o[7] = f2b(a1.w);
    *(u16x8*)(out + base) = o;
  }
}

// ====== K-loop, 256x128 tile, 512 thr (8 waves), wave-tile 64x64 ======
DEVI void kloop(const u16* Ab, const u16* Bb, int lda, int ldb, int K,
                u16* sA, u16* sB, int tid, int wr, int wc, f32x4 (&acc)[4][4]) {
  const int lane = tid & 63;
  const int ar = lane & 15;
  const int sr = tid >> 3;                        // 0..63
  const int scL = (tid & 7) << 3;
  const int scG = ((tid & 7) ^ (sr & 7)) << 3;    // swizzled global col granule

  const int l7 = lane & 7, l16 = lane >> 4;
  const int p0b = (l16 ^ l7) << 4;
  const int offA0 = (wr + ar) * 128 + p0b;
  const int offB0 = (wc + ar) * 128 + p0b;
  const char* sAc = (const char*)sA;
  const char* sBc = (const char*)sB;

  for (int k0 = 0; k0 < K; k0 += 64) {
#pragma unroll
    for (int it = 0; it < 4; ++it) {              // A: 256 rows
      int r = it * 64 + sr;
      __builtin_amdgcn_global_load_lds(
          (__attribute__((address_space(1))) void*)(Ab + (size_t)r * lda + k0 + scG),
          (__attribute__((address_space(3))) void*)(sA + r * 64 + scL), 16, 0, 0);
    }
#pragma unroll
    for (int it = 0; it < 2; ++it) {              // B: 128 rows
      int r = it * 64 + sr;
      __builtin_amdgcn_global_load_lds(
          (__attribute__((address_space(1))) void*)(Bb + (size_t)r * ldb + k0 + scG),
          (__attribute__((address_space(3))) void*)(sB + r * 64 + scL), 16, 0, 0);
    }
    __syncthreads();
#pragma unroll
    for (int half = 0; half < 2; ++half) {
      const int px = half ? 64 : 0;
      bf16x8 af[4], bfr[4];
#pragma unroll
      for (int t = 0; t < 4; ++t)
        af[t] = *(const bf16x8*)(sAc + ((offA0 ^ px) + t * 2048));
#pragma unroll
      for (int t = 0; t < 4; ++t)
        bfr[t] = *(const bf16x8*)(sBc + ((offB0 ^ px) + t * 2048));
#pragma unroll
      for (int tm = 0; tm < 4; ++tm)
#pragma unroll
        for (int tn = 0; tn < 4; ++tn)
          acc[tm][tn] = __builtin_amdgcn_mfma_f32_16x16x32_bf16(
              af[tm], bfr[tn], acc[tm][tn], 0, 0, 0);
    }
    __syncthreads();
  }
}

// ====== K-loop, 128x64 tile, 512 thr (8 waves), wave-tile 32x32, BK=128 =====
// LDS rows are 128 u16 (256B, 16 granules). Involution: LDS[r][g] holds
// global[r][g ^ (r&7)] (bits 0-2). Same verified scheme as R21's BK=128.
DEVI void kloop_pv64(const u16* Ab, const u16* Bb, int lda, int ldb, int K,
                     u16* sA, u16* sB, int tid, int wr, int wc,
                     f32x4 (&acc)[2][2]) {
  const int lane = tid & 63;
  const int ar = lane & 15;
  const int srow = tid >> 4;                      // 0..31
  const int scL = (tid & 15) << 3;                // dest elem off (granule tid&15)
  const int scG = ((tid & 15) ^ (srow & 7)) << 3; // swizzled source granule

  const int l7 = lane & 7, l16 = lane >> 4;
  const int gbase = l16 ^ (l7 & 3);               // read granule bits 0-1
  const int gb2 = (l7 >> 2) & 1;                  // read granule bit-2 XOR
  const int rowA = (wr + ar) * 256;               // byte offset of row
  const int rowB = (wc + ar) * 256;
  const char* sAc = (const char*)sA;
  const char* sBc = (const char*)sB;

  for (int k0 = 0; k0 < K; k0 += 128) {
#pragma unroll
    for (int it = 0; it < 4; ++it) {              // A: 128 rows, 32/iter
      int r = it * 32 + srow;
      __builtin_amdgcn_global_load_lds(
          (__attribute__((address_space(1))) void*)(Ab + (size_t)r * lda + k0 + scG),
          (__attribute__((address_space(3))) void*)(sA + r * 128 + scL), 16, 0, 0);
    }
#pragma unroll
    for (int it = 0; it < 2; ++it) {              // B: 64 rows, 32/iter
      int r = it * 32 + srow;
      __builtin_amdgcn_global_load_lds(
          (__attribute__((address_space(1))) void*)(Bb + (size_t)r * ldb + k0 + scG),
          (__attribute__((address_space(3))) void*)(sB + r * 128 + scL), 16, 0, 0);
    }
    __syncthreads();
#pragma unroll
    for (int kq = 0; kq < 4; ++kq) {              // 4 k-quarters of 32
      const int g = ((((kq ^ gb2) << 2) | gbase) << 4);
      bf16x8 af[2], bfr[2];
#pragma unroll
      for (int t = 0; t < 2; ++t)
        af[t] = *(const bf16x8*)(sAc + rowA + t * 4096 + g);
#pragma unroll
      for (int t = 0; t < 2; ++t)
        bfr[t] = *(const bf16x8*)(sBc + rowB + t * 4096 + g);
#pragma unroll
      for (int tm = 0; tm < 2; ++tm)
#pragma unroll
        for (int tn = 0; tn < 2; ++tn)
          acc[tm][tn] = __builtin_amdgcn_mfma_f32_16x16x32_bf16(
              af[tm], bfr[tn], acc[tm][tn], 0, 0, 0);
    }
    __syncthreads();
  }
}

// ---------------- merged GEMM1 + V'^T (512 thr, 256x128 tile) ----------------
__global__ __launch_bounds__(512)
void gemm_qkv(const u16* __restrict__ cB, const u16* __restrict__ WqkB,
              u16* __restrict__ qks,
              const u16* __restrict__ WpsB, const u16* __restrict__ WpqB,
              const u16* __restrict__ qBf, const u16* __restrict__ sBf,
              u16* __restrict__ VsT, u16* __restrict__ VqT,
              float sq, float sk) {
  __shared__ __align__(16) u16 sA[256 * 64];
  __shared__ __align__(16) u16 sB[128 * 64];
  int b = blockIdx.x;
  b = (b & 7) * 96 + (b >> 3);         // XCD-chunked swizzle (768 = 8*96)
  const u16* Ap; const u16* Bp; u16* op;
  int bx, by, ldc;
  bool proj;
  if (b < 512) {
    proj = true;  bx = b & 15; by = b >> 4;
    Ap = cB; Bp = WqkB; op = qks; ldc = 2048;
  } else {
    proj = false;
    int b2 = b - 512;
    int z = b2 >> 7, rem = b2 & 127;
    bx = rem & 31; by = rem >> 5;
    Ap = z ? WpqB : WpsB; Bp = z ? sBf : qBf; op = z ? VqT : VsT; ldc = 4096;
  }
  const int tid = threadIdx.x;
  const int lane = tid & 63;
  const int wave = tid >> 6;           // 0..7
  const int wr = (wave >> 1) * 64;     // 0,64,128,192
  const int wc = (wave & 1) * 64;      // 0,64

  f32x4 acc[4][4];
#pragma unroll
  for (int i = 0; i < 4; ++i)
#pragma unroll
    for (int j = 0; j < 4; ++j) acc[i][j] = f32x4{0.f, 0.f, 0.f, 0.f};

  kloop(Ap + (size_t)(by * 256) * 1024, Bp + (size_t)(bx * 128) * 1024,
        1024, 1024, 1024, sA, sB, tid, wr, wc, acc);

  const int qr = (lane >> 4) * 4;
  const int qc = lane & 15;
#pragma unroll
  for (int tm = 0; tm < 4; ++tm)
#pragma unroll
    for (int r = 0; r < 4; ++r) {
      int row = by * 256 + wr + tm * 16 + qr + r;
#pragma unroll
      for (int tn = 0; tn < 4; ++tn) {
        int col = bx * 128 + wc + tn * 16 + qc;
        float sc = proj ? ((col < 1024) ? sq : sk) : 1.0f;
        op[(size_t)row * ldc + col] = f2b(acc[tm][tn][r] * sc);
      }
    }
}

// ---------------- scores GEMM (R0-exact 256x128 config) ----------------
// Grid dim3(64,32): bx = 128-col tile, by = 256-row tile, x fastest
// (consecutive blocks share the A panel). No XCD swizzle (R13: FETCH 3x).
__global__ __launch_bounds__(512)
void gemm_scores(const u16* __restrict__ qks, u16* __restrict__ Pcq,
                 u16* __restrict__ Pqc, float* __restrict__ rowsum) {
  __shared__ __align__(16) u16 sA[256 * 64];
  __shared__ __align__(16) u16 sB[128 * 64];
  const int tid = threadIdx.x;
  const int lane = tid & 63;
  const int wave = tid >> 6;
  const int wr = (wave >> 1) * 64;
  const int wc = (wave & 1) * 64;
  const int bx = blockIdx.x;            // 0..63
  const int by = blockIdx.y;            // 0..31

  f32x4 acc[4][4];
#pragma unroll
  for (int i = 0; i < 4; ++i)
#pragma unroll
    for (int j = 0; j < 4; ++j) acc[i][j] = f32x4{0.f, 0.f, 0.f, 0.f};

  kloop(qks + (size_t)(by * 256) * 2048,
        qks + 1024 + (size_t)(bx * 128) * 2048,
        2048, 2048, 1024, sA, sB, tid, wr, wc, acc);

  const int qr = (lane >> 4) * 4;
  const int qc = lane & 15;
  const bool top = (by < 16);
  const bool left = (bx < 32);
  u16* pdst = nullptr;
  if (top && !left) pdst = Pcq;
  if (!top && left) pdst = Pqc;
  const int growb = by * 256 + wr;
  const int rbase = growb - (top ? 0 : 4096);
  const int cbase = bx * 128 + wc - (left ? 0 : 4096);
#pragma unroll
  for (int tm = 0; tm < 4; ++tm) {
    float e[4][4];
    float rsum[4] = {0.f, 0.f, 0.f, 0.f};
#pragma unroll
    for (int tn = 0; tn < 4; ++tn)
#pragma unroll
      for (int r = 0; r < 4; ++r) {
        e[tn][r] = exp2_hw(acc[tm][tn][r]);  // scores pre-scaled by log2(e)
        rsum[r] += e[tn][r];
      }
#pragma unroll
    for (int r = 0; r < 4; ++r) {
      float v = rsum[r];
      v += __shfl_xor(v, 1);
      v += __shfl_xor(v, 2);
      v += __shfl_xor(v, 4);
      v += __shfl_xor(v, 8);
      if ((lane & 15) == 0)
        atomicAdd(&rowsum[growb + tm * 16 + qr + r], v);
    }
    if (pdst) {
#pragma unroll
      for (int tn = 0; tn < 4; ++tn)
#pragma unroll
        for (int r = 0; r < 4; ++r) {
          int row = rbase + tm * 16 + qr + r;
          pdst[(size_t)row * 4096 + cbase + tn * 16 + qc] = f2b(e[tn][r]);
        }
    }
  }
}

// ---------------- PV GEMM: 128x64 tile, 8 waves, BK=128, 3 blk/CU -----------
// grid 1024 (XCD swz, 1024 = 8*128 bijective); wave grid 4Mx2N, wave-tile
// 32x32, acc[2][2]. LDS 48KB -> 3 blocks/CU, 24 waves/CU.
__global__ __launch_bounds__(512)
void gemm_pv(const u16* __restrict__ Pcq, const u16* __restrict__ Pqc,
             const u16* __restrict__ VsT, const u16* __restrict__ VqT,
             const float* __restrict__ rowsum,
             float* __restrict__ out0, float* __restrict__ out1) {
  __shared__ __align__(16) u16 sA[128 * 128];
  __shared__ __align__(16) u16 sB[64 * 128];
  const int tid = threadIdx.x;
  const int lane = tid & 63;
  const int wave = tid >> 6;            // 0..7
  const int wr = (wave >> 1) * 32;      // 0,32,64,96
  const int wc = (wave & 1) * 32;       // 0,32
  int b = blockIdx.x;
  int swz = (b & 7) * 128 + (b >> 3);   // 1024 = 8*128, bijective
  const int z = swz >> 9;               // 0,1
  const int rem = swz & 511;
  const int by = rem >> 4;              // 0..31 (128-row tiles within half)
  const int bx = rem & 15;              // 0..15 (64-col tiles)

  f32x4 acc[2][2];
#pragma unroll
  for (int i = 0; i < 2; ++i)
#pragma unroll
    for (int j = 0; j < 2; ++j) acc[i][j] = f32x4{0.f, 0.f, 0.f, 0.f};

  kloop_pv64((z ? Pqc : Pcq) + (size_t)(by * 128) * 4096,
             (z ? VqT : VsT) + (size_t)(bx * 64) * 4096,
             4096, 4096, 4096, sA, sB, tid, wr, wc, acc);

  const int qr = (lane >> 4) * 4;
  const int qc = lane & 15;
  float* of = z ? out1 : out0;
  const float* rsz = rowsum + z * 4096;
#pragma unroll
  for (int tm = 0; tm < 2; ++tm)
#pragma unroll
    for (int r = 0; r < 4; ++r) {
      int row = by * 128 + wr + tm * 16 + qr + r;
      float inv = 1.0f / rsz[row];
#pragma unroll
      for (int tn = 0; tn < 2; ++tn) {
        int col = bx * 64 + wc + tn * 16 + qc;
        of[(size_t)row * 1024 + col] = acc[tm][tn][r] * inv;
      }
    }
}

// ---------------- launcher ----------------

extern "C" void kernel_launch(void* const* d_in, const int* in_sizes, int n_in,
                              void* d_out, int out_size, void* d_ws, size_t ws_size,
                              hipStream_t stream) {
  (void)in_sizes; (void)n_in; (void)out_size; (void)ws_size;
  const float* query = (const float*)d_in[0];
  const float* s     = (const float*)d_in[1];
  const float* tg    = (const float*)d_in[2];
  const float* Wqkv  = (const float*)d_in[3];
  const float* Wps   = (const float*)d_in[4];
  const float* Wpq   = (const float*)d_in[5];
  float* out = (float*)d_out;

  char* ws = (char*)d_ws;
  u16* cB     = (u16*)ws; ws += (size_t)8192 * 1024 * 2;   // [s+tg ; query] bf16
  u16* sBf    = (u16*)ws; ws += (size_t)4096 * 1024 * 2;   // s bf16
  u16* qks    = (u16*)ws; ws += (size_t)8192 * 2048 * 2;   // [q*SCALE*LOG2E | k*SCALE]
  u16* WqkB   = (u16*)ws; ws += (size_t)2048 * 1024 * 2;
  u16* WpsB   = (u16*)ws; ws += (size_t)1024 * 1024 * 2;
  u16* WpqB   = (u16*)ws; ws += (size_t)1024 * 1024 * 2;
  u16* VsT    = (u16*)ws; ws += (size_t)1024 * 4096 * 2;   // Wps@query^T
  u16* VqT    = (u16*)ws; ws += (size_t)1024 * 4096 * 2;   // Wpq@s^T
  u16* Pcq    = (u16*)ws; ws += (size_t)4096 * 4096 * 2;
  u16* Pqc    = (u16*)ws; ws += (size_t)4096 * 4096 * 2;
  float* rowsum = (float*)ws;  // 8192 floats

  const u16* qBf = cB + (size_t)4096 * 1024;  // query bf16 rows of cB

  const float SCALE = 0.17677669529663687f;   // 1024^-0.25
  const float LOG2E = 1.4426950408889634f;

  prep_all<<<6152, 256, 0, stream>>>(query, s, tg, Wqkv, Wps, Wpq,
                                     cB, sBf, WqkB, WpsB, WpqB, rowsum);
  // merged GEMM1 + V'^T pair (768 blocks of 512 thr)
  gemm_qkv<<<768, 512, 0, stream>>>(cB, WqkB, qks, WpsB, WpqB, qBf, sBf,
                                    VsT, VqT, SCALE * LOG2E, SCALE);
  // GEMM2: scores (8192x8192) -> 2^score quadrants (bf16) + row sums
  gemm_scores<<<dim3(64, 32), 512, 0, stream>>>(qks, Pcq, Pqc, rowsum);
  // PV (z in swizzle), fp32 straight to d_out, 128x64 tiles, 3 blk/CU
  gemm_pv<<<1024, 512, 0, stream>>>(Pcq, Pqc, VsT, VqT, rowsum,
                                    out, out + (size_t)4096 * 1024);
}

// Round 13
// 395.818 us; speedup vs baseline: 1.1054x; 1.1054x over previous
//
#include <hip/hip_runtime.h>

// Attention block: x_s = softmax(qk^T)[:4096,4096:] @ query @ Wps^T
//                  x_q = softmax(qk^T)[4096:,:4096] @ s     @ Wpq^T
// R23 = R21 verbatim (pre-committed revert; R22's 128x64-tile PV regressed
// 396.5 -> 437.6: wave-tile 32x32 = 4 MFMA/phase vs 4 b128 reads at 24
// waves/CU saturated the LDS port — 3blk/CU preference only holds with
// wave-tile >= 32x64). Measured optima, bracketed from both sides:
//   scores: 256x128/8w/2-barrier (128sq=198, 256x128=~167 BEST, 256sq=223;
//           schedule ports dead x3, fp8 dead, XCD-swz dead)
//   PV:     128x128/8w/BK=128/2blk-CU (4w=R19, 8w=R20 +4.5, BK128=R21 +11.5,
//           smaller tile=R22 -41, K-split=R18 -22)
//   qkv:    256x128 + XCD swizzle (R13 +16 with PV change)
// prep (R0) unchanged.

typedef unsigned short u16;
typedef __bf16 bf16x8 __attribute__((ext_vector_type(8)));
typedef float f32x4 __attribute__((ext_vector_type(4)));
typedef unsigned short u16x8 __attribute__((ext_vector_type(8)));

#define DEVI static __device__ __forceinline__

DEVI u16 f2b(float f) {  // fp32 -> bf16 round-to-nearest-even
  unsigned int u = __float_as_uint(f);
  u += 0x7fffu + ((u >> 16) & 1u);
  return (u16)(u >> 16);
}

DEVI float exp2_hw(float x) {  // v_exp_f32: 2^x
  float r;
  asm("v_exp_f32 %0, %1" : "=v"(r) : "v"(x));
  return r;
}

// ---------------- fused prep (unchanged) ----------------
__global__ void prep_all(const float* __restrict__ query, const float* __restrict__ s,
                         const float* __restrict__ tg, const float* __restrict__ w0,
                         const float* __restrict__ w1, const float* __restrict__ w2,
                         u16* __restrict__ cB, u16* __restrict__ sBf,
                         u16* __restrict__ o0, u16* __restrict__ o1,
                         u16* __restrict__ o2, float* __restrict__ rowsum) {
  int b = blockIdx.x;
  if (b >= 6144) {
    int i = (b - 6144) * 1024 + (int)threadIdx.x * 4;
    rowsum[i] = 0.f; rowsum[i + 1] = 0.f; rowsum[i + 2] = 0.f; rowsum[i + 3] = 0.f;
    return;
  }
  if (b < 4096) {
    int base = (b * 256 + threadIdx.x) << 3;
    int row = base >> 10;
    u16x8 o;
    if (row < 4096) {
      float4 a0 = *(const float4*)(s + base);
      float4 a1 = *(const float4*)(s + base + 4);
      float4 b0 = *(const float4*)(tg + base);
      float4 b1 = *(const float4*)(tg + base + 4);
      u16x8 os;
      os[0] = f2b(a0.x); os[1] = f2b(a0.y); os[2] = f2b(a0.z); os[3] = f2b(a0.w);
      os[4] = f2b(a1.x); os[5] = f2b(a1.y); os[6] = f2b(a1.z); os[7] = f2b(a1.w);
      *(u16x8*)(sBf + base) = os;
      o[0] = f2b(a0.x + b0.x); o[1] = f2b(a0.y + b0.y);
      o[2] = f2b(a0.z + b0.z); o[3] = f2b(a0.w + b0.w);
      o[4] = f2b(a1.x + b1.x); o[5] = f2b(a1.y + b1.y);
      o[6] = f2b(a1.z + b1.z); o[7] = f2b(a1.w + b1.w);
    } else {
      int qb = base - 4096 * 1024;
      float4 a0 = *(const float4*)(query + qb);
      float4 a1 = *(const float4*)(query + qb + 4);
      o[0] = f2b(a0.x); o[1] = f2b(a0.y); o[2] = f2b(a0.z); o[3] = f2b(a0.w);
      o[4] = f2b(a1.x); o[5] = f2b(a1.y); o[6] = f2b(a1.z); o[7] = f2b(a1.w);
    }
    *(u16x8*)(cB + base) = o;
  } else {
    const float* in; u16* out; int lb;
    if (b < 5120)      { in = w0; out = o0; lb = b - 4096; }
    else if (b < 5632) { in = w1; out = o1; lb = b - 5120; }
    else               { in = w2; out = o2; lb = b - 5632; }
    int base = (lb * 256 + threadIdx.x) << 3;
    float4 a0 = *(const float4*)(in + base);
    float4 a1 = *(const float4*)(in + base + 4);
    u16x8 o;
    o[0] = f2b(a0.x); o[1] = f2b(a0.y); o[2] = f2b(a0.z); o[3] = f2b(a0.w);
    o[4] = f2b(a1.x); o[5] = f2b(a1.y); o[6] = f2b(a1.z); o[7] = f2b(a1.w);
    *(u16x8*)(out + base) = o;
  }
}

// ====== K-loop, 256x128 tile, 512 thr (8 waves), wave-tile 64x64 ======
DEVI void kloop(const u16* Ab, const u16* Bb, int lda, int ldb, int K,
                u16* sA, u16* sB, int tid, int wr, int wc, f32x4 (&acc)[4][4]) {
  const int lane = tid & 63;
  const int ar = lane & 15;
  const int sr = tid >> 3;                        // 0..63
  const int scL = (tid & 7) << 3;
  const int scG = ((tid & 7) ^ (sr & 7)) << 3;    // swizzled global col granule

  const int l7 = lane & 7, l16 = lane >> 4;
  const int p0b = (l16 ^ l7) << 4;
  const int offA0 = (wr + ar) * 128 + p0b;
  const int offB0 = (wc + ar) * 128 + p0b;
  const char* sAc = (const char*)sA;
  const char* sBc = (const char*)sB;

  for (int k0 = 0; k0 < K; k0 += 64) {
#pragma unroll
    for (int it = 0; it < 4; ++it) {              // A: 256 rows
      int r = it * 64 + sr;
      __builtin_amdgcn_global_load_lds(
          (__attribute__((address_space(1))) void*)(Ab + (size_t)r * lda + k0 + scG),
          (__attribute__((address_space(3))) void*)(sA + r * 64 + scL), 16, 0, 0);
    }
#pragma unroll
    for (int it = 0; it < 2; ++it) {              // B: 128 rows
      int r = it * 64 + sr;
      __builtin_amdgcn_global_load_lds(
          (__attribute__((address_space(1))) void*)(Bb + (size_t)r * ldb + k0 + scG),
          (__attribute__((address_space(3))) void*)(sB + r * 64 + scL), 16, 0, 0);
    }
    __syncthreads();
#pragma unroll
    for (int half = 0; half < 2; ++half) {
      const int px = half ? 64 : 0;
      bf16x8 af[4], bfr[4];
#pragma unroll
      for (int t = 0; t < 4; ++t)
        af[t] = *(const bf16x8*)(sAc + ((offA0 ^ px) + t * 2048));
#pragma unroll
      for (int t = 0; t < 4; ++t)
        bfr[t] = *(const bf16x8*)(sBc + ((offB0 ^ px) + t * 2048));
#pragma unroll
      for (int tm = 0; tm < 4; ++tm)
#pragma unroll
        for (int tn = 0; tn < 4; ++tn)
          acc[tm][tn] = __builtin_amdgcn_mfma_f32_16x16x32_bf16(
              af[tm], bfr[tn], acc[tm][tn], 0, 0, 0);
    }
    __syncthreads();
  }
}

// ====== K-loop, 128x128 tile, 512 thr (8 waves), wave-tile 32x64, BK=128 ====
// LDS rows are 128 u16 (256B, 16 granules of 16B). Involution: LDS[r][g]
// holds global[r][g ^ (r&7)] (bits 0-2 only). Stage dest is lane-contiguous
// (rows of 16 granules in lane order) as global_load_lds requires.
DEVI void kloop128w8b(const u16* Ab, const u16* Bb, int lda, int ldb, int K,
                      u16* sA, u16* sB, int tid, int wr, int wc,
                      f32x4 (&acc)[2][4]) {
  const int lane = tid & 63;
  const int ar = lane & 15;
  const int srow = tid >> 4;                      // 0..31
  const int scL = (tid & 15) << 3;                // dest elem off (granule tid&15)
  const int scG = ((tid & 15) ^ (srow & 7)) << 3; // swizzled source granule

  const int l7 = lane & 7, l16 = lane >> 4;
  const int gbase = l16 ^ (l7 & 3);               // read granule bits 0-1
  const int gb2 = (l7 >> 2) & 1;                  // read granule bit-2 XOR
  const int rowA = (wr + ar) * 256;               // byte offset of row
  const int rowB = (wc + ar) * 256;
  const char* sAc = (const char*)sA;
  const char* sBc = (const char*)sB;

  for (int k0 = 0; k0 < K; k0 += 128) {
#pragma unroll
    for (int it = 0; it < 4; ++it) {              // A: 128 rows, 32/iter
      int r = it * 32 + srow;
      __builtin_amdgcn_global_load_lds(
          (__attribute__((address_space(1))) void*)(Ab + (size_t)r * lda + k0 + scG),
          (__attribute__((address_space(3))) void*)(sA + r * 128 + scL), 16, 0, 0);
    }
#pragma unroll
    for (int it = 0; it < 4; ++it) {              // B: 128 rows
      int r = it * 32 + srow;
      __builtin_amdgcn_global_load_lds(
          (__attribute__((address_space(1))) void*)(Bb + (size_t)r * ldb + k0 + scG),
          (__attribute__((address_space(3))) void*)(sB + r * 128 + scL), 16, 0, 0);
    }
    __syncthreads();
#pragma unroll
    for (int kq = 0; kq < 4; ++kq) {              // 4 k-quarters of 32
      const int g = ((((kq ^ gb2) << 2) | gbase) << 4);
      bf16x8 af[2], bfr[4];
#pragma unroll
      for (int t = 0; t < 2; ++t)
        af[t] = *(const bf16x8*)(sAc + rowA + t * 4096 + g);
#pragma unroll
      for (int t = 0; t < 4; ++t)
        bfr[t] = *(const bf16x8*)(sBc + rowB + t * 4096 + g);
#pragma unroll
      for (int tm = 0; tm < 2; ++tm)
#pragma unroll
        for (int tn = 0; tn < 4; ++tn)
          acc[tm][tn] = __builtin_amdgcn_mfma_f32_16x16x32_bf16(
              af[tm], bfr[tn], acc[tm][tn], 0, 0, 0);
    }
    __syncthreads();
  }
}

// ---------------- merged GEMM1 + V'^T (512 thr, 256x128 tile) ----------------
__global__ __launch_bounds__(512)
void gemm_qkv(const u16* __restrict__ cB, const u16* __restrict__ WqkB,
              u16* __restrict__ qks,
              const u16* __restrict__ WpsB, const u16* __restrict__ WpqB,
              const u16* __restrict__ qBf, const u16* __restrict__ sBf,
              u16* __restrict__ VsT, u16* __restrict__ VqT,
              float sq, float sk) {
  __shared__ __align__(16) u16 sA[256 * 64];
  __shared__ __align__(16) u16 sB[128 * 64];
  int b = blockIdx.x;
  b = (b & 7) * 96 + (b >> 3);         // XCD-chunked swizzle (768 = 8*96)
  const u16* Ap; const u16* Bp; u16* op;
  int bx, by, ldc;
  bool proj;
  if (b < 512) {
    proj = true;  bx = b & 15; by = b >> 4;
    Ap = cB; Bp = WqkB; op = qks; ldc = 2048;
  } else {
    proj = false;
    int b2 = b - 512;
    int z = b2 >> 7, rem = b2 & 127;
    bx = rem & 31; by = rem >> 5;
    Ap = z ? WpqB : WpsB; Bp = z ? sBf : qBf; op = z ? VqT : VsT; ldc = 4096;
  }
  const int tid = threadIdx.x;
  const int lane = tid & 63;
  const int wave = tid >> 6;           // 0..7
  const int wr = (wave >> 1) * 64;     // 0,64,128,192
  const int wc = (wave & 1) * 64;      // 0,64

  f32x4 acc[4][4];
#pragma unroll
  for (int i = 0; i < 4; ++i)
#pragma unroll
    for (int j = 0; j < 4; ++j) acc[i][j] = f32x4{0.f, 0.f, 0.f, 0.f};

  kloop(Ap + (size_t)(by * 256) * 1024, Bp + (size_t)(bx * 128) * 1024,
        1024, 1024, 1024, sA, sB, tid, wr, wc, acc);

  const int qr = (lane >> 4) * 4;
  const int qc = lane & 15;
#pragma unroll
  for (int tm = 0; tm < 4; ++tm)
#pragma unroll
    for (int r = 0; r < 4; ++r) {
      int row = by * 256 + wr + tm * 16 + qr + r;
#pragma unroll
      for (int tn = 0; tn < 4; ++tn) {
        int col = bx * 128 + wc + tn * 16 + qc;
        float sc = proj ? ((col < 1024) ? sq : sk) : 1.0f;
        op[(size_t)row * ldc + col] = f2b(acc[tm][tn][r] * sc);
      }
    }
}

// ---------------- scores GEMM (R0-exact 256x128 config) ----------------
// Grid dim3(64,32): bx = 128-col tile, by = 256-row tile, x fastest
// (consecutive blocks share the A panel). No XCD swizzle (R13: FETCH 3x).
__global__ __launch_bounds__(512)
void gemm_scores(const u16* __restrict__ qks, u16* __restrict__ Pcq,
                 u16* __restrict__ Pqc, float* __restrict__ rowsum) {
  __shared__ __align__(16) u16 sA[256 * 64];
  __shared__ __align__(16) u16 sB[128 * 64];
  const int tid = threadIdx.x;
  const int lane = tid & 63;
  const int wave = tid >> 6;
  const int wr = (wave >> 1) * 64;
  const int wc = (wave & 1) * 64;
  const int bx = blockIdx.x;            // 0..63
  const int by = blockIdx.y;            // 0..31

  f32x4 acc[4][4];
#pragma unroll
  for (int i = 0; i < 4; ++i)
#pragma unroll
    for (int j = 0; j < 4; ++j) acc[i][j] = f32x4{0.f, 0.f, 0.f, 0.f};

  kloop(qks + (size_t)(by * 256) * 2048,
        qks + 1024 + (size_t)(bx * 128) * 2048,
        2048, 2048, 1024, sA, sB, tid, wr, wc, acc);

  const int qr = (lane >> 4) * 4;
  const int qc = lane & 15;
  const bool top = (by < 16);
  const bool left = (bx < 32);
  u16* pdst = nullptr;
  if (top && !left) pdst = Pcq;
  if (!top && left) pdst = Pqc;
  const int growb = by * 256 + wr;
  const int rbase = growb - (top ? 0 : 4096);
  const int cbase = bx * 128 + wc - (left ? 0 : 4096);
#pragma unroll
  for (int tm = 0; tm < 4; ++tm) {
    float e[4][4];
    float rsum[4] = {0.f, 0.f, 0.f, 0.f};
#pragma unroll
    for (int tn = 0; tn < 4; ++tn)
#pragma unroll
      for (int r = 0; r < 4; ++r) {
        e[tn][r] = exp2_hw(acc[tm][tn][r]);  // scores pre-scaled by log2(e)
        rsum[r] += e[tn][r];
      }
#pragma unroll
    for (int r = 0; r < 4; ++r) {
      float v = rsum[r];
      v += __shfl_xor(v, 1);
      v += __shfl_xor(v, 2);
      v += __shfl_xor(v, 4);
      v += __shfl_xor(v, 8);
      if ((lane & 15) == 0)
        atomicAdd(&rowsum[growb + tm * 16 + qr + r], v);
    }
    if (pdst) {
#pragma unroll
      for (int tn = 0; tn < 4; ++tn)
#pragma unroll
        for (int r = 0; r < 4; ++r) {
          int row = rbase + tm * 16 + qr + r;
          pdst[(size_t)row * 4096 + cbase + tn * 16 + qc] = f2b(e[tn][r]);
        }
    }
  }
}

// ---------------- PV GEMM: 128x128, 8 waves, BK=128, 2 blk/CU ---------------
// grid 512 (XCD swz); wave grid 4x2, wave-tile 32x64, acc[2][4].
// LDS 64KB (2 x 128x128 u16) -> still 2 blocks/CU (grid-capped anyway);
// barrier pairs per block halve: 64 -> 32 over K=4096.
__global__ __launch_bounds__(512)
void gemm_pv(const u16* __restrict__ Pcq, const u16* __restrict__ Pqc,
             const u16* __restrict__ VsT, const u16* __restrict__ VqT,
             const float* __restrict__ rowsum,
             float* __restrict__ out0, float* __restrict__ out1) {
  __shared__ __align__(16) u16 sA[128 * 128];
  __shared__ __align__(16) u16 sB[128 * 128];
  const int tid = threadIdx.x;
  const int lane = tid & 63;
  const int wave = tid >> 6;            // 0..7
  const int wr = (wave >> 1) * 32;      // 0,32,64,96
  const int wc = (wave & 1) * 64;       // 0,64
  int b = blockIdx.x;
  int swz = (b & 7) * 64 + (b >> 3);    // 512 = 8*64, bijective
  const int z = swz >> 8;
  const int rem = swz & 255;
  const int by = rem >> 3;              // 0..31 (128-row tiles)
  const int bx = rem & 7;               // 0..7  (128-col tiles)

  f32x4 acc[2][4];
#pragma unroll
  for (int i = 0; i < 2; ++i)
#pragma unroll
    for (int j = 0; j < 4; ++j) acc[i][j] = f32x4{0.f, 0.f, 0.f, 0.f};

  kloop128w8b((z ? Pqc : Pcq) + (size_t)(by * 128) * 4096,
              (z ? VqT : VsT) + (size_t)(bx * 128) * 4096,
              4096, 4096, 4096, sA, sB, tid, wr, wc, acc);

  const int qr = (lane >> 4) * 4;
  const int qc = lane & 15;
  float* of = z ? out1 : out0;
  const float* rsz = rowsum + z * 4096;
#pragma unroll
  for (int tm = 0; tm < 2; ++tm)
#pragma unroll
    for (int r = 0; r < 4; ++r) {
      int row = by * 128 + wr + tm * 16 + qr + r;
      float inv = 1.0f / rsz[row];
#pragma unroll
      for (int tn = 0; tn < 4; ++tn) {
        int col = bx * 128 + wc + tn * 16 + qc;
        of[(size_t)row * 1024 + col] = acc[tm][tn][r] * inv;
      }
    }
}

// ---------------- launcher ----------------

extern "C" void kernel_launch(void* const* d_in, const int* in_sizes, int n_in,
                              void* d_out, int out_size, void* d_ws, size_t ws_size,
                              hipStream_t stream) {
  (void)in_sizes; (void)n_in; (void)out_size; (void)ws_size;
  const float* query = (const float*)d_in[0];
  const float* s     = (const float*)d_in[1];
  const float* tg    = (const float*)d_in[2];
  const float* Wqkv  = (const float*)d_in[3];
  const float* Wps   = (const float*)d_in[4];
  const float* Wpq   = (const float*)d_in[5];
  float* out = (float*)d_out;

  char* ws = (char*)d_ws;
  u16* cB     = (u16*)ws; ws += (size_t)8192 * 1024 * 2;   // [s+tg ; query] bf16
  u16* sBf    = (u16*)ws; ws += (size_t)4096 * 1024 * 2;   // s bf16
  u16* qks    = (u16*)ws; ws += (size_t)8192 * 2048 * 2;   // [q*SCALE*LOG2E | k*SCALE]
  u16* WqkB   = (u16*)ws; ws += (size_t)2048 * 1024 * 2;
  u16* WpsB   = (u16*)ws; ws += (size_t)1024 * 1024 * 2;
  u16* WpqB   = (u16*)ws; ws += (size_t)1024 * 1024 * 2;
  u16* VsT    = (u16*)ws; ws += (size_t)1024 * 4096 * 2;   // Wps@query^T
  u16* VqT    = (u16*)ws; ws += (size_t)1024 * 4096 * 2;   // Wpq@s^T
  u16* Pcq    = (u16*)ws; ws += (size_t)4096 * 4096 * 2;
  u16* Pqc    = (u16*)ws; ws += (size_t)4096 * 4096 * 2;
  float* rowsum = (float*)ws;  // 8192 floats

  const u16* qBf = cB + (size_t)4096 * 1024;  // query bf16 rows of cB

  const float SCALE = 0.17677669529663687f;   // 1024^-0.25
  const float LOG2E = 1.4426950408889634f;

  prep_all<<<6152, 256, 0, stream>>>(query, s, tg, Wqkv, Wps, Wpq,
                                     cB, sBf, WqkB, WpsB, WpqB, rowsum);
  // merged GEMM1 + V'^T pair (768 blocks of 512 thr)
  gemm_qkv<<<768, 512, 0, stream>>>(cB, WqkB, qks, WpsB, WpqB, qBf, sBf,
                                    VsT, VqT, SCALE * LOG2E, SCALE);
  // GEMM2: scores (8192x8192) -> 2^score quadrants (bf16) + row sums
  gemm_scores<<<dim3(64, 32), 512, 0, stream>>>(qks, Pcq, Pqc, rowsum);
  // PV (z in swizzle), fp32 straight to d_out, 8 waves, BK=128
  gemm_pv<<<512, 512, 0, stream>>>(Pcq, Pqc, VsT, VqT, rowsum,
                                   out, out + (size_t)4096 * 1024);
}